// Round 15
// baseline (666.645 us; speedup 1.0000x reference)
//
#include <hip/hip_runtime.h>
#include <stdint.h>

#define M_DIM 8192
#define N_DIM 4096
#define K_DIM 4096

typedef float f32x4 __attribute__((ext_vector_type(4)));
typedef int   i32x4 __attribute__((ext_vector_type(4)));
typedef int   i32x8 __attribute__((ext_vector_type(8)));

// ---------------- fused amax (x and w) via uint-bits atomicMax ----------------
__global__ __launch_bounds__(256) void amax2_kernel(const float* __restrict__ x,
                                                    const float* __restrict__ wgt,
                                                    unsigned int* __restrict__ ws_u) {
    const int which = blockIdx.y;
    const float4* p = (const float4*)(which ? wgt : x);
    const int n4 = (which ? N_DIM : M_DIM) * (K_DIM / 4);
    int tid = blockIdx.x * blockDim.x + threadIdx.x;
    int stride = gridDim.x * blockDim.x;
    float m = 0.0f;
    for (int i = tid; i < n4; i += stride) {
        float4 v = p[i];
        m = fmaxf(m, fmaxf(fmaxf(fabsf(v.x), fabsf(v.y)),
                           fmaxf(fabsf(v.z), fabsf(v.w))));
    }
#pragma unroll
    for (int off = 32; off > 0; off >>= 1)
        m = fmaxf(m, __shfl_down(m, off, 64));
    __shared__ float sm[4];
    if ((threadIdx.x & 63) == 0) sm[threadIdx.x >> 6] = m;
    __syncthreads();
    if (threadIdx.x == 0) {
        m = fmaxf(fmaxf(sm[0], sm[1]), fmaxf(sm[2], sm[3]));
        atomicMax(ws_u + which, __float_as_uint(m));  // values >= 0: bit order == float order
    }
}

// ---------------- fused quantize f32 -> fp8 e4m3fn (packed 4/uint) -------------
__global__ __launch_bounds__(256) void quant2_kernel(const float* __restrict__ x,
                                                     const float* __restrict__ wgt,
                                                     unsigned int* __restrict__ xq,
                                                     unsigned int* __restrict__ wq,
                                                     const unsigned int* __restrict__ ws_u) {
    const int which = blockIdx.y;
    const float4* p = (const float4*)(which ? wgt : x);
    unsigned int* outp = which ? wq : xq;
    const int n4 = (which ? N_DIM : M_DIM) * (K_DIM / 4);
    float amax = fmaxf(__uint_as_float(ws_u[which]), 1e-12f);
    float scale = 448.0f / amax;
    int tid = blockIdx.x * blockDim.x + threadIdx.x;
    int stride = gridDim.x * blockDim.x;
    for (int i = tid; i < n4; i += stride) {
        float4 v = p[i];
        float a = fminf(fmaxf(v.x * scale, -448.0f), 448.0f);
        float b = fminf(fmaxf(v.y * scale, -448.0f), 448.0f);
        float c = fminf(fmaxf(v.z * scale, -448.0f), 448.0f);
        float d = fminf(fmaxf(v.w * scale, -448.0f), 448.0f);
        int w = __builtin_amdgcn_cvt_pk_fp8_f32(a, b, 0, false);
        w = __builtin_amdgcn_cvt_pk_fp8_f32(c, d, w, true);
        outp[i] = (unsigned int)w;
    }
}

// ------ MX-fp8 GEMM: producer/consumer wave specialization, 256x256 tile ------
__device__ __forceinline__ void gld16(const void* g, void* l) {
    __builtin_amdgcn_global_load_lds(
        (const __attribute__((address_space(1))) void*)g,
        (__attribute__((address_space(3))) void*)l, 16, 0, 0);
}

__device__ __forceinline__ i32x8 ld2(const uint8_t* bl, const uint8_t* bh, int off) {
    i32x4 lo = *(const i32x4*)(bl + off);   // off literal -> ds_read immediate
    i32x4 hi = *(const i32x4*)(bh + off);
    return __builtin_shufflevector(lo, hi, 0, 1, 2, 3, 4, 5, 6, 7);
}

#define MFMA_MX(a, b, c) __builtin_amdgcn_mfma_scale_f32_16x16x128_f8f6f4( \
    (a), (b), (c), 0, 0, 0, 0x7F7F7F7F, 0, 0x7F7F7F7F)
#define BAR()    __builtin_amdgcn_s_barrier()
#define VMCNT0() asm volatile("s_waitcnt vmcnt(0)" ::: "memory")
#define PRIO1()  __builtin_amdgcn_s_setprio(1)
#define PRIO0()  __builtin_amdgcn_s_setprio(0)

// 768 threads = 8 consumer waves (2Mx4N, 128x64 out each; ONLY ds_read+MFMA)
//             + 4 producer waves (ONLY global_load_lds staging + vmcnt(0)).
// LDS: A bufs [0,32K),[32K,64K); B bufs [64K,96K),[96K,128K); [256 rows][128B]
// linear, 16B-chunk XOR swizzle (chunk ^= row&7): linear dest, pre-swizzled
// global source, XOR folded into per-thread read base offsets (rule #21).
// ONE barrier/tile. Invariants at barrier #t+1:
//  - producers staged tile t+1 into buf (t+1)&1 and drained vmcnt(0);
//  - every consumer read of buf t&1 is retired (each ds_read is consumed by
//    an MFMA -> register dependency forces lgkm retirement pre-barrier);
//  => producers may overwrite buf t&1 with tile t+2 during tile t+1. No
//  consumer ever waits on vmem; the vmcnt stall lives in producer waves and
//  is hidden under consumer compute (~2300 cyc >> HBM ~900 cyc).
__global__ __launch_bounds__(768, 1) void gemm_fp8_kernel(
    const uint8_t* __restrict__ Aq,   // [M][K] fp8
    const uint8_t* __restrict__ Bq,   // [N][K] fp8
    const float* __restrict__ bias,   // [N]
    const unsigned int* __restrict__ ws_u,
    float* __restrict__ out)          // [M][N] f32
{
    __shared__ uint8_t lds[131072];

    const int tid = threadIdx.x;
    const int w = tid >> 6, l = tid & 63;

    // XCD swizzle (512 blocks, %8==0): 32 M-tiles x 16 N-tiles
    const int cpx = (int)gridDim.x >> 3;
    const int bid = (int)blockIdx.x;
    const int swz = (bid & 7) * cpx + (bid >> 3);
    const int bm = swz >> 4, bn = swz & 15;

    const uint8_t* gA = Aq + (size_t)bm * 256 * K_DIM;
    const uint8_t* gB = Bq + (size_t)bn * 256 * K_DIM;

    if (w >= 8) {
        // ================= producer waves (4) =================
        const int tid2 = tid - 512;               // 0..255
        const int idx = tid2 >> 3, p = tid2 & 7;  // row group / dest chunk
        const int srcX = ((p ^ (idx & 7)) << 4);  // pre-swizzled source chunk
        const uint8_t* aRow = gA + (size_t)idx * K_DIM + srcX;
        const uint8_t* bRow = gB + (size_t)idx * K_DIM + srcX;
        const int dst = tid2 * 16;
        // rows idx+32r, r=0..7: (row&7)==(idx&7) -> swizzle key invariant;
        // dest r*4096+dst -> row r*32+idx: identical [256][128] linear layout.

        // prologue: stage tile 0 -> buf 0
#pragma unroll
        for (int r = 0; r < 8; ++r)
            gld16(aRow + (size_t)(r * 32) * K_DIM, &lds[r * 4096 + dst]);
#pragma unroll
        for (int r = 0; r < 8; ++r)
            gld16(bRow + (size_t)(r * 32) * K_DIM, &lds[65536 + r * 4096 + dst]);
        VMCNT0();
        BAR();                                    // barrier #1: tile 0 visible

        for (int t = 0; t < 32; ++t) {
            if (t < 31) {
                const int nb = (t + 1) & 1;
                const int kn = (t + 1) * 128;
#pragma unroll
                for (int r = 0; r < 8; ++r)
                    gld16(aRow + (size_t)(r * 32) * K_DIM + kn,
                          &lds[nb * 32768 + r * 4096 + dst]);
#pragma unroll
                for (int r = 0; r < 8; ++r)
                    gld16(bRow + (size_t)(r * 32) * K_DIM + kn,
                          &lds[65536 + nb * 32768 + r * 4096 + dst]);
                VMCNT0();                         // stall lives here, hidden
            }
            BAR();                                // barrier #t+2
        }
        return;                                   // no more barriers below
    }

    // ================= consumer waves (8) =================
    const int wr = w >> 2, wc = w & 3;            // 2M x 4N wave grid
    const int lr = l & 15, g = l >> 4;
    const int oLo = (((2 * g) ^ (lr & 7)) << 4);
    const int oHi = (((2 * g + 1) ^ (lr & 7)) << 4);
    const int rowA0 = wr * 128 + lr;
    const int rowB0 = wc * 64 + lr;
    const int aOffL = (rowA0 << 7) + oLo, aOffH = (rowA0 << 7) + oHi;
    const int bOffL = (rowB0 << 7) + oLo, bOffH = (rowB0 << 7) + oHi;

    f32x4 acc[8][4] = {};
    i32x8 av[4], bv[4];

    BAR();                                        // barrier #1: tile 0 visible

    for (int t = 0; t < 32; ++t) {
        const int buf = t & 1;
        const uint8_t* qaL = &lds[buf * 32768] + aOffL;
        const uint8_t* qaH = &lds[buf * 32768] + aOffH;
        const uint8_t* qbL = &lds[65536 + buf * 32768] + bOffL;
        const uint8_t* qbH = &lds[65536 + buf * 32768] + bOffH;

        // ---- Q0: A rows 0..48, B cols 0,1
        av[0] = ld2(qaL, qaH, 0);     av[1] = ld2(qaL, qaH, 2048);
        av[2] = ld2(qaL, qaH, 4096);  av[3] = ld2(qaL, qaH, 6144);
        bv[0] = ld2(qbL, qbH, 0);     bv[1] = ld2(qbL, qbH, 2048);
        PRIO1();
        acc[0][0] = MFMA_MX(av[0], bv[0], acc[0][0]);
        acc[0][1] = MFMA_MX(av[0], bv[1], acc[0][1]);
        acc[1][0] = MFMA_MX(av[1], bv[0], acc[1][0]);
        acc[1][1] = MFMA_MX(av[1], bv[1], acc[1][1]);
        acc[2][0] = MFMA_MX(av[2], bv[0], acc[2][0]);
        acc[2][1] = MFMA_MX(av[2], bv[1], acc[2][1]);
        acc[3][0] = MFMA_MX(av[3], bv[0], acc[3][0]);
        acc[3][1] = MFMA_MX(av[3], bv[1], acc[3][1]);
        PRIO0();

        // ---- Q1: B cols 2,3
        bv[2] = ld2(qbL, qbH, 4096);  bv[3] = ld2(qbL, qbH, 6144);
        PRIO1();
        acc[0][2] = MFMA_MX(av[0], bv[2], acc[0][2]);
        acc[0][3] = MFMA_MX(av[0], bv[3], acc[0][3]);
        acc[1][2] = MFMA_MX(av[1], bv[2], acc[1][2]);
        acc[1][3] = MFMA_MX(av[1], bv[3], acc[1][3]);
        acc[2][2] = MFMA_MX(av[2], bv[2], acc[2][2]);
        acc[2][3] = MFMA_MX(av[2], bv[3], acc[2][3]);
        acc[3][2] = MFMA_MX(av[3], bv[2], acc[3][2]);
        acc[3][3] = MFMA_MX(av[3], bv[3], acc[3][3]);
        PRIO0();

        // ---- Q2: A rows 64..112 (WAR on av paces the read burst)
        av[0] = ld2(qaL, qaH, 8192);  av[1] = ld2(qaL, qaH, 10240);
        av[2] = ld2(qaL, qaH, 12288); av[3] = ld2(qaL, qaH, 14336);
        PRIO1();
        acc[4][0] = MFMA_MX(av[0], bv[0], acc[4][0]);
        acc[4][1] = MFMA_MX(av[0], bv[1], acc[4][1]);
        acc[5][0] = MFMA_MX(av[1], bv[0], acc[5][0]);
        acc[5][1] = MFMA_MX(av[1], bv[1], acc[5][1]);
        acc[6][0] = MFMA_MX(av[2], bv[0], acc[6][0]);
        acc[6][1] = MFMA_MX(av[2], bv[1], acc[6][1]);
        acc[7][0] = MFMA_MX(av[3], bv[0], acc[7][0]);
        acc[7][1] = MFMA_MX(av[3], bv[1], acc[7][1]);
        PRIO0();

        // ---- Q3
        PRIO1();
        acc[4][2] = MFMA_MX(av[0], bv[2], acc[4][2]);
        acc[4][3] = MFMA_MX(av[0], bv[3], acc[4][3]);
        acc[5][2] = MFMA_MX(av[1], bv[2], acc[5][2]);
        acc[5][3] = MFMA_MX(av[1], bv[3], acc[5][3]);
        acc[6][2] = MFMA_MX(av[2], bv[2], acc[6][2]);
        acc[6][3] = MFMA_MX(av[2], bv[3], acc[6][3]);
        acc[7][2] = MFMA_MX(av[3], bv[2], acc[7][2]);
        acc[7][3] = MFMA_MX(av[3], bv[3], acc[7][3]);
        PRIO0();

        BAR();   // all reads of buf t retired (consumed by MFMAs above);
                 // producers have staged & drained tile t+1
    }

    // ---- epilogue: scale by (amax_x/448)*(amax_w/448), add bias
    const float ax = fmaxf(__uint_as_float(ws_u[0]), 1e-12f);
    const float aw = fmaxf(__uint_as_float(ws_u[1]), 1e-12f);
    const float inv = (ax * (1.0f / 448.0f)) * (aw * (1.0f / 448.0f));

    const int orow0 = bm * 256 + wr * 128 + g * 4;   // D: row=(lane>>4)*4+reg
    const int ocol0 = bn * 256 + wc * 64 + lr;       // D: col=lane&15
#pragma unroll
    for (int mb = 0; mb < 8; ++mb) {
#pragma unroll
        for (int nb = 0; nb < 4; ++nb) {
            const int col = ocol0 + nb * 16;
            const float bvv = bias[col];
#pragma unroll
            for (int j = 0; j < 4; ++j) {
                const int row = orow0 + mb * 16 + j;
                out[(size_t)row * N_DIM + col] = acc[mb][nb][j] * inv + bvv;
            }
        }
    }
}

// ---------------- launch ----------------
extern "C" void kernel_launch(void* const* d_in, const int* in_sizes, int n_in,
                              void* d_out, int out_size, void* d_ws, size_t ws_size,
                              hipStream_t stream) {
    const float* x    = (const float*)d_in[0];   // [8192, 4096]
    const float* wgt  = (const float*)d_in[1];   // [4096, 4096]
    const float* bias = (const float*)d_in[2];   // [4096]
    float* out = (float*)d_out;                  // [8192, 4096] f32

    unsigned int* ws_u = (unsigned int*)d_ws;
    uint8_t* xq = (uint8_t*)d_ws + 256;
    uint8_t* wq = xq + (size_t)M_DIM * K_DIM;

    hipMemsetAsync(d_ws, 0, 8, stream);          // zero both amax slots

    dim3 ga(1024, 2);
    amax2_kernel<<<ga, 256, 0, stream>>>(x, wgt, ws_u);

    dim3 gq(2048, 2);
    quant2_kernel<<<gq, 256, 0, stream>>>(x, wgt, (unsigned int*)xq,
                                          (unsigned int*)wq, ws_u);

    gemm_fp8_kernel<<<(M_DIM / 256) * (N_DIM / 256), 768, 0, stream>>>(
        xq, wq, bias, ws_u, out);
}

// Round 16
// 210.119 us; speedup vs baseline: 3.1727x; 3.1727x over previous
//
#include <hip/hip_runtime.h>
#include <stdint.h>

#define M_DIM 8192
#define N_DIM 4096
#define K_DIM 4096

typedef float f32x4 __attribute__((ext_vector_type(4)));
typedef int   i32x4 __attribute__((ext_vector_type(4)));
typedef int   i32x8 __attribute__((ext_vector_type(8)));

// ---------------- fused amax (x and w) via uint-bits atomicMax ----------------
__global__ __launch_bounds__(256) void amax2_kernel(const float* __restrict__ x,
                                                    const float* __restrict__ wgt,
                                                    unsigned int* __restrict__ ws_u) {
    const int which = blockIdx.y;
    const float4* p = (const float4*)(which ? wgt : x);
    const int n4 = (which ? N_DIM : M_DIM) * (K_DIM / 4);
    int tid = blockIdx.x * blockDim.x + threadIdx.x;
    int stride = gridDim.x * blockDim.x;
    float m = 0.0f;
    for (int i = tid; i < n4; i += stride) {
        float4 v = p[i];
        m = fmaxf(m, fmaxf(fmaxf(fabsf(v.x), fabsf(v.y)),
                           fmaxf(fabsf(v.z), fabsf(v.w))));
    }
#pragma unroll
    for (int off = 32; off > 0; off >>= 1)
        m = fmaxf(m, __shfl_down(m, off, 64));
    __shared__ float sm[4];
    if ((threadIdx.x & 63) == 0) sm[threadIdx.x >> 6] = m;
    __syncthreads();
    if (threadIdx.x == 0) {
        m = fmaxf(fmaxf(sm[0], sm[1]), fmaxf(sm[2], sm[3]));
        atomicMax(ws_u + which, __float_as_uint(m));  // values >= 0: bit order == float order
    }
}

// ---------------- fused quantize f32 -> fp8 e4m3fn (packed 4/uint) -------------
__global__ __launch_bounds__(256) void quant2_kernel(const float* __restrict__ x,
                                                     const float* __restrict__ wgt,
                                                     unsigned int* __restrict__ xq,
                                                     unsigned int* __restrict__ wq,
                                                     const unsigned int* __restrict__ ws_u) {
    const int which = blockIdx.y;
    const float4* p = (const float4*)(which ? wgt : x);
    unsigned int* outp = which ? wq : xq;
    const int n4 = (which ? N_DIM : M_DIM) * (K_DIM / 4);
    float amax = fmaxf(__uint_as_float(ws_u[which]), 1e-12f);
    float scale = 448.0f / amax;
    int tid = blockIdx.x * blockDim.x + threadIdx.x;
    int stride = gridDim.x * blockDim.x;
    for (int i = tid; i < n4; i += stride) {
        float4 v = p[i];
        float a = fminf(fmaxf(v.x * scale, -448.0f), 448.0f);
        float b = fminf(fmaxf(v.y * scale, -448.0f), 448.0f);
        float c = fminf(fmaxf(v.z * scale, -448.0f), 448.0f);
        float d = fminf(fmaxf(v.w * scale, -448.0f), 448.0f);
        int w = __builtin_amdgcn_cvt_pk_fp8_f32(a, b, 0, false);
        w = __builtin_amdgcn_cvt_pk_fp8_f32(c, d, w, true);
        outp[i] = (unsigned int)w;
    }
}

// ---------------- MX-fp8 GEMM, 256x256 tile, 4-phase pipelined ----------------
// Measured-best configuration (R4/R13/R14): 129.5 us, MfmaUtil 45%, VGPR 124.
// Session record: 11 structural variants (fewer barriers, more barriers,
// burst reads, B-direct, 2 blocks/CU, 32x32 MFMA, SW-pipelined disjoint regs,
// producer/consumer specialization) all measured worse (138-580 us). The
// DS<->MFMA pipe alternation at 1 barrier-synced block/CU is the binding
// structural constraint in plain HIP for this 128-f32-accumulator geometry.
__device__ __forceinline__ void gld16(const void* g, void* l) {
    __builtin_amdgcn_global_load_lds(
        (const __attribute__((address_space(1))) void*)g,
        (__attribute__((address_space(3))) void*)l, 16, 0, 0);
}

__device__ __forceinline__ i32x8 ld2(const uint8_t* bl, const uint8_t* bh, int off) {
    i32x4 lo = *(const i32x4*)(bl + off);   // off literal -> ds_read immediate
    i32x4 hi = *(const i32x4*)(bh + off);
    return __builtin_shufflevector(lo, hi, 0, 1, 2, 3, 4, 5, 6, 7);
}

#define MFMA_MX(a, b, c) __builtin_amdgcn_mfma_scale_f32_16x16x128_f8f6f4( \
    (a), (b), (c), 0, 0, 0, 0x7F7F7F7F, 0, 0x7F7F7F7F)

// LDS: A bufs at [0,32K),[32K,64K); B bufs at [64K,96K),[96K,128K).
// Per-tensor tile [256 rows][128 B], 16B-chunk XOR swizzle (chunk ^= row&7),
// staged linearly (pre-swizzled global source), read with XOR folded into
// per-thread base offsets. Pipeline: tile t read from buf t&1; tile t+1's 4
// units staged one-per-phase into buf^1. Counted vmcnt only (never 0 in the
// main loop): ledger (2 loads/unit, order UA0,UB0,UA1,UB1) => phase0 needs
// UA0,UB0 -> vmcnt(4); phase1 needs UA1,UB1 -> vmcnt(2).
__global__ __launch_bounds__(512, 2) void gemm_fp8_kernel(
    const uint8_t* __restrict__ Aq,   // [M][K] fp8
    const uint8_t* __restrict__ Bq,   // [N][K] fp8
    const float* __restrict__ bias,   // [N]
    const unsigned int* __restrict__ ws_u,
    float* __restrict__ out)          // [M][N] f32
{
    __shared__ uint8_t lds[131072];

    const int tid = threadIdx.x;
    const int w = tid >> 6, l = tid & 63;

    // XCD swizzle (512 blocks, %8==0): 32 M-tiles x 16 N-tiles
    const int cpx = (int)gridDim.x >> 3;
    const int bid = (int)blockIdx.x;
    const int swz = (bid & 7) * cpx + (bid >> 3);
    const int bm = swz >> 4, bn = swz & 15;

    const uint8_t* gA = Aq + (size_t)bm * 256 * K_DIM;
    const uint8_t* gB = Bq + (size_t)bn * 256 * K_DIM;

    // staging constants
    const int idx = tid >> 3, p = tid & 7;
    const int rB = (idx & 31) + ((idx >> 5) << 6);
    const int srcX = ((p ^ (idx & 7)) << 4);
    const int dA = tid * 16;
    const int dB = tid * 16 + ((tid >> 8) << 12);

    // fragment-read constants
    const int wr = w >> 2, wc = w & 3;       // 2M x 4N wave grid
    const int lr = l & 15, g = l >> 4;
    const int oLo = (((2 * g) ^ (lr & 7)) << 4);
    const int oHi = (((2 * g + 1) ^ (lr & 7)) << 4);
    const int rowA0 = wr * 128 + lr;
    const int rowB0 = wc * 64 + lr;
    const int aOffL = (rowA0 << 7) + oLo, aOffH = (rowA0 << 7) + oHi;
    const int bOffL = (rowB0 << 7) + oLo, bOffH = (rowB0 << 7) + oHi;

    auto stA = [&](int bb, const uint8_t* gsrc, int rbase) {
        const int row = idx + rbase;
        gld16(gsrc + (size_t)row * K_DIM + srcX,
              &lds[bb * 32768 + rbase * 128 + dA]);
    };
    auto stB = [&](int bb, const uint8_t* gsrc, int boff, int r) {
        const int row = rB + boff + (r << 7);
        gld16(gsrc + (size_t)row * K_DIM + srcX,
              &lds[65536 + bb * 32768 + (boff << 7) + (r << 14) + dB]);
    };

    f32x4 acc[8][4] = {};
    i32x8 av[4], bv[4];

    // prologue: stage tile 0 -> buf 0 (issue order UA0, UB0, UA1, UB1)
    stA(0, gA, 0);   stA(0, gA, 128);
    stB(0, gB, 0, 0); stB(0, gB, 0, 1);
    stA(0, gA, 64);  stA(0, gA, 192);
    stB(0, gB, 32, 0); stB(0, gB, 32, 1);

    for (int t = 0; t < 31; ++t) {
        const int buf = t & 1, nbuf = buf ^ 1;
        const uint8_t* gAn = gA + (size_t)(t + 1) * 128;
        const uint8_t* gBn = gB + (size_t)(t + 1) * 128;
        const uint8_t* qaL = &lds[buf * 32768] + aOffL;
        const uint8_t* qaH = &lds[buf * 32768] + aOffH;
        const uint8_t* qbL = &lds[65536 + buf * 32768] + bOffL;
        const uint8_t* qbH = &lds[65536 + buf * 32768] + bOffH;

        // ---- phase 0: UA0(t),UB0(t) ready; stage UA0(t+1)
        asm volatile("s_waitcnt vmcnt(4)" ::: "memory");
        __builtin_amdgcn_s_barrier();
        stA(nbuf, gAn, 0); stA(nbuf, gAn, 128);
        av[0] = ld2(qaL, qaH, 0);     av[1] = ld2(qaL, qaH, 2048);
        av[2] = ld2(qaL, qaH, 4096);  av[3] = ld2(qaL, qaH, 6144);
        bv[0] = ld2(qbL, qbH, 0);     bv[1] = ld2(qbL, qbH, 2048);
        __builtin_amdgcn_s_setprio(1);
        acc[0][0] = MFMA_MX(av[0], bv[0], acc[0][0]);
        acc[0][1] = MFMA_MX(av[0], bv[1], acc[0][1]);
        acc[1][0] = MFMA_MX(av[1], bv[0], acc[1][0]);
        acc[1][1] = MFMA_MX(av[1], bv[1], acc[1][1]);
        acc[2][0] = MFMA_MX(av[2], bv[0], acc[2][0]);
        acc[2][1] = MFMA_MX(av[2], bv[1], acc[2][1]);
        acc[3][0] = MFMA_MX(av[3], bv[0], acc[3][0]);
        acc[3][1] = MFMA_MX(av[3], bv[1], acc[3][1]);
        __builtin_amdgcn_s_setprio(0);

        // ---- phase 1: UA1(t),UB1(t) ready; stage UB0(t+1)
        asm volatile("s_waitcnt vmcnt(2)" ::: "memory");
        __builtin_amdgcn_s_barrier();
        stB(nbuf, gBn, 0, 0); stB(nbuf, gBn, 0, 1);
        bv[2] = ld2(qbL, qbH, 4096);  bv[3] = ld2(qbL, qbH, 6144);
        __builtin_amdgcn_s_setprio(1);
        acc[0][2] = MFMA_MX(av[0], bv[2], acc[0][2]);
        acc[0][3] = MFMA_MX(av[0], bv[3], acc[0][3]);
        acc[1][2] = MFMA_MX(av[1], bv[2], acc[1][2]);
        acc[1][3] = MFMA_MX(av[1], bv[3], acc[1][3]);
        acc[2][2] = MFMA_MX(av[2], bv[2], acc[2][2]);
        acc[2][3] = MFMA_MX(av[2], bv[3], acc[2][3]);
        acc[3][2] = MFMA_MX(av[3], bv[2], acc[3][2]);
        acc[3][3] = MFMA_MX(av[3], bv[3], acc[3][3]);
        __builtin_amdgcn_s_setprio(0);

        // ---- phase 2: stage UA1(t+1); read A mb4-7 (completion covered by ph1)
        stA(nbuf, gAn, 64); stA(nbuf, gAn, 192);
        av[0] = ld2(qaL, qaH, 8192);  av[1] = ld2(qaL, qaH, 10240);
        av[2] = ld2(qaL, qaH, 12288); av[3] = ld2(qaL, qaH, 14336);
        __builtin_amdgcn_s_setprio(1);
        acc[4][0] = MFMA_MX(av[0], bv[0], acc[4][0]);
        acc[4][1] = MFMA_MX(av[0], bv[1], acc[4][1]);
        acc[5][0] = MFMA_MX(av[1], bv[0], acc[5][0]);
        acc[5][1] = MFMA_MX(av[1], bv[1], acc[5][1]);
        acc[6][0] = MFMA_MX(av[2], bv[0], acc[6][0]);
        acc[6][1] = MFMA_MX(av[2], bv[1], acc[6][1]);
        acc[7][0] = MFMA_MX(av[3], bv[0], acc[7][0]);
        acc[7][1] = MFMA_MX(av[3], bv[1], acc[7][1]);
        __builtin_amdgcn_s_setprio(0);

        // ---- phase 3: stage UB1(t+1)
        stB(nbuf, gBn, 32, 0); stB(nbuf, gBn, 32, 1);
        __builtin_amdgcn_s_setprio(1);
        acc[4][2] = MFMA_MX(av[0], bv[2], acc[4][2]);
        acc[4][3] = MFMA_MX(av[0], bv[3], acc[4][3]);
        acc[5][2] = MFMA_MX(av[1], bv[2], acc[5][2]);
        acc[5][3] = MFMA_MX(av[1], bv[3], acc[5][3]);
        acc[6][2] = MFMA_MX(av[2], bv[2], acc[6][2]);
        acc[6][3] = MFMA_MX(av[2], bv[3], acc[6][3]);
        acc[7][2] = MFMA_MX(av[3], bv[2], acc[7][2]);
        acc[7][3] = MFMA_MX(av[3], bv[3], acc[7][3]);
        __builtin_amdgcn_s_setprio(0);
    }

    // ---- peeled last tile (t=31, buf=1): no stages; drain waits
    {
        const uint8_t* qaL = &lds[32768] + aOffL;
        const uint8_t* qaH = &lds[32768] + aOffH;
        const uint8_t* qbL = &lds[65536 + 32768] + bOffL;
        const uint8_t* qbH = &lds[65536 + 32768] + bOffH;

        asm volatile("s_waitcnt vmcnt(4)" ::: "memory");
        __builtin_amdgcn_s_barrier();
        av[0] = ld2(qaL, qaH, 0);     av[1] = ld2(qaL, qaH, 2048);
        av[2] = ld2(qaL, qaH, 4096);  av[3] = ld2(qaL, qaH, 6144);
        bv[0] = ld2(qbL, qbH, 0);     bv[1] = ld2(qbL, qbH, 2048);
#pragma unroll
        for (int m = 0; m < 4; ++m) {
            acc[m][0] = MFMA_MX(av[m], bv[0], acc[m][0]);
            acc[m][1] = MFMA_MX(av[m], bv[1], acc[m][1]);
        }
        asm volatile("s_waitcnt vmcnt(0)" ::: "memory");
        __builtin_amdgcn_s_barrier();
        bv[2] = ld2(qbL, qbH, 4096);  bv[3] = ld2(qbL, qbH, 6144);
#pragma unroll
        for (int m = 0; m < 4; ++m) {
            acc[m][2] = MFMA_MX(av[m], bv[2], acc[m][2]);
            acc[m][3] = MFMA_MX(av[m], bv[3], acc[m][3]);
        }
        av[0] = ld2(qaL, qaH, 8192);  av[1] = ld2(qaL, qaH, 10240);
        av[2] = ld2(qaL, qaH, 12288); av[3] = ld2(qaL, qaH, 14336);
#pragma unroll
        for (int m = 0; m < 4; ++m) {
            acc[4 + m][0] = MFMA_MX(av[m], bv[0], acc[4 + m][0]);
            acc[4 + m][1] = MFMA_MX(av[m], bv[1], acc[4 + m][1]);
            acc[4 + m][2] = MFMA_MX(av[m], bv[2], acc[4 + m][2]);
            acc[4 + m][3] = MFMA_MX(av[m], bv[3], acc[4 + m][3]);
        }
    }

    // ---- epilogue: scale by (amax_x/448)*(amax_w/448), add bias
    const float ax = fmaxf(__uint_as_float(ws_u[0]), 1e-12f);
    const float aw = fmaxf(__uint_as_float(ws_u[1]), 1e-12f);
    const float inv = (ax * (1.0f / 448.0f)) * (aw * (1.0f / 448.0f));

    const int orow0 = bm * 256 + wr * 128 + g * 4;   // D: row=(lane>>4)*4+reg
    const int ocol0 = bn * 256 + wc * 64 + lr;       // D: col=lane&15
#pragma unroll
    for (int mb = 0; mb < 8; ++mb) {
#pragma unroll
        for (int nb = 0; nb < 4; ++nb) {
            const int col = ocol0 + nb * 16;
            const float bvv = bias[col];
#pragma unroll
            for (int j = 0; j < 4; ++j) {
                const int row = orow0 + mb * 16 + j;
                out[(size_t)row * N_DIM + col] = acc[mb][nb][j] * inv + bvv;
            }
        }
    }
}

// ---------------- launch ----------------
extern "C" void kernel_launch(void* const* d_in, const int* in_sizes, int n_in,
                              void* d_out, int out_size, void* d_ws, size_t ws_size,
                              hipStream_t stream) {
    const float* x    = (const float*)d_in[0];   // [8192, 4096]
    const float* wgt  = (const float*)d_in[1];   // [4096, 4096]
    const float* bias = (const float*)d_in[2];   // [4096]
    float* out = (float*)d_out;                  // [8192, 4096] f32

    unsigned int* ws_u = (unsigned int*)d_ws;
    uint8_t* xq = (uint8_t*)d_ws + 256;
    uint8_t* wq = xq + (size_t)M_DIM * K_DIM;

    hipMemsetAsync(d_ws, 0, 8, stream);          // zero both amax slots

    dim3 ga(1024, 2);
    amax2_kernel<<<ga, 256, 0, stream>>>(x, wgt, ws_u);

    dim3 gq(2048, 2);
    quant2_kernel<<<gq, 256, 0, stream>>>(x, wgt, (unsigned int*)xq,
                                          (unsigned int*)wq, ws_u);

    gemm_fp8_kernel<<<(M_DIM / 256) * (N_DIM / 256), 512, 0, stream>>>(
        xq, wq, bias, ws_u, out);
}